// Round 6
// baseline (218.685 us; speedup 1.0000x reference)
//
#include <hip/hip_runtime.h>

// Problem constants (from reference setup_inputs)
#define BB 8
#define CC 3
#define HH 512
#define WW 1024
#define HW (HH * WW)            // 524288 = 2^19
#define NTOT (BB * HW)          // 4194304
#define SAME_RANGE 0.2f

// Partition of (source -> target) pairs:
//   displacement <= R in both coords  -> handled by the block/step owning the
//                                        TARGET row via the source window
//   displacement  > R in either coord -> exact outlier list (~57 of 4.2M)
#define R 4
#define TX 128                  // strip width (x)
#define SEGY 64                 // target rows per block
#define TY 8                    // target rows per marching step
#define NSTEP (SEGY / TY)       // 8
#define WROWS (TY + 2 * R)      // 16 source window rows per step
#define GX ((TX + 2 * R) / 4)   // 34 float4 groups per window row (136 cols)
#define NGRP (WROWS * GX)       // 544 groups per step
#define NT 512                  // threads per block (8 waves)
#define TT (TX * TY)            // 1024 accumulator slots per step
#define CAP 16384               // outlier list capacity (~57 used)
#define D_SENT 0x7F7F7F7F       // > any depth bit pattern (depth in [0,1))

// Pass 1 (vectorized): outlier sources appended to global list.
__global__ void prep_kernel(const float* __restrict__ flow,
                            const float* __restrict__ depth,
                            const float* __restrict__ obj,
                            int* __restrict__ counter,
                            float* __restrict__ list) {
    int i = blockIdx.x * blockDim.x + threadIdx.x;   // one float4 group (4 px)
    int b = i >> 17;                                 // (4i) / HW
    int rem = (i << 2) & (HW - 1);                   // 4-aligned source offset
    int y = rem >> 10;
    int x0 = rem & (WW - 1);
    const float4 fx4 = *(const float4*)(flow + (size_t)(b * 2 + 0) * HW + rem);
    const float4 fy4 = *(const float4*)(flow + (size_t)(b * 2 + 1) * HW + rem);
    const float fxs[4] = {fx4.x, fx4.y, fx4.z, fx4.w};
    const float fys[4] = {fy4.x, fy4.y, fy4.z, fy4.w};
    #pragma unroll
    for (int k = 0; k < 4; ++k) {
        int x = x0 + k;
        float px = fminf(fmaxf(fxs[k] + (float)x, 0.0f), (float)(WW - 1));
        float py = fminf(fmaxf(fys[k] + (float)y, 0.0f), (float)(HH - 1));
        int xi = (int)rintf(px);    // round-half-to-even == jnp.round
        int yi = (int)rintf(py);
        int dx = xi - x; if (dx < 0) dx = -dx;
        int dy = yi - y; if (dy < 0) dy = -dy;
        if (dx > R || dy > R) {
            int idx = b * HW + yi * WW + xi;
            int srem = rem + k;
            float d = depth[(size_t)b * HW + srem];
            int pos = atomicAdd(counter, 1);
            if (pos < CAP) {
                float* e = list + (size_t)pos * 8;
                e[0] = __int_as_float(idx);
                e[1] = d;
                e[2] = obj[((size_t)b * CC + 0) * HW + srem];
                e[3] = obj[((size_t)b * CC + 1) * HW + srem];
                e[4] = obj[((size_t)b * CC + 2) * HW + srem];
            }
        }
    }
}

// Pass 2: marching-strip LDS-scatter. Block owns a 128x64 target region and
// processes it in 8 steps of 8 target rows. Per step: read the 16x136 source
// window (544B contiguous segments; 8 rows re-read from hot L1/L2), LDS
// z-buffer min, keep-test + LDS adds (operands register-resident), fused
// store+reset. Outlier list folded per step. No global atomics.
__global__ __launch_bounds__(NT) void gather_kernel(
        const float* __restrict__ obj,
        const float* __restrict__ flow,
        const float* __restrict__ depth,
        const int* __restrict__ counter,
        const float* __restrict__ list,
        float* __restrict__ out) {
    __shared__ int   s_dmin[TT];
    __shared__ float s_s0[TT], s_s1[TT], s_s2[TT], s_cnt[TT];

    const int b   = blockIdx.z;
    const int x0  = blockIdx.x * TX;
    const int y0  = blockIdx.y * SEGY;
    const int tid = threadIdx.x;

    const float* flowx = flow + (size_t)(b * 2 + 0) * HW;
    const float* flowy = flow + (size_t)(b * 2 + 1) * HW;
    const float* dep_b = depth + (size_t)b * HW;
    const float* ob0 = obj + ((size_t)b * CC + 0) * HW;
    const float* ob1 = obj + ((size_t)b * CC + 1) * HW;
    const float* ob2 = obj + ((size_t)b * CC + 2) * HW;

    // Initial reset: thread t<256 owns slots [4t, 4t+4) (same slots it will
    // store+reset each step -> no extra barrier between store and reset).
    if (tid < 256) {
        #pragma unroll
        for (int k = 0; k < 4; ++k) {
            int i = tid * 4 + k;
            s_dmin[i] = D_SENT;
            s_s0[i] = 0.0f; s_s1[i] = 0.0f; s_s2[i] = 0.0f; s_cnt[i] = 0.0f;
        }
    }
    int noutl = *counter;
    if (noutl > CAP) noutl = CAP;
    __syncthreads();

    for (int s = 0; s < NSTEP; ++s) {
        const int ty0 = y0 + s * TY;

        // Phase A: window loads + target calc + LDS z-buffer min.
        int   tl[8];
        float dp[8], a0[8], a1[8], a2[8];
        #pragma unroll
        for (int e = 0; e < 2; ++e) {
            #pragma unroll
            for (int k = 0; k < 4; ++k) tl[e * 4 + k] = -1;
            int g = tid + e * NT;
            if (g < NGRP) {
                int row = g / GX;            // 0..15
                int col = g - row * GX;      // 0..33
                int gy  = ty0 - R + row;
                int gx0 = x0 - R + col * 4;  // 16B aligned; never straddles edge
                if (gy >= 0 && gy < HH && gx0 >= 0 && gx0 < WW) {
                    size_t roff = (size_t)gy * WW + gx0;
                    const float4 fx4 = *(const float4*)(flowx + roff);
                    const float4 fy4 = *(const float4*)(flowy + roff);
                    const float4 d4  = *(const float4*)(dep_b + roff);
                    const float4 A0  = *(const float4*)(ob0 + roff);
                    const float4 A1  = *(const float4*)(ob1 + roff);
                    const float4 A2  = *(const float4*)(ob2 + roff);
                    const float fxs[4] = {fx4.x, fx4.y, fx4.z, fx4.w};
                    const float fys[4] = {fy4.x, fy4.y, fy4.z, fy4.w};
                    const float ds[4]  = {d4.x, d4.y, d4.z, d4.w};
                    const float s0v[4] = {A0.x, A0.y, A0.z, A0.w};
                    const float s1v[4] = {A1.x, A1.y, A1.z, A1.w};
                    const float s2v[4] = {A2.x, A2.y, A2.z, A2.w};
                    #pragma unroll
                    for (int k = 0; k < 4; ++k) {
                        int x = gx0 + k;
                        float px = fminf(fmaxf(fxs[k] + (float)x, 0.0f), (float)(WW - 1));
                        float py = fminf(fmaxf(fys[k] + (float)gy, 0.0f), (float)(HH - 1));
                        int xi = (int)rintf(px);
                        int yi = (int)rintf(py);
                        int ddx = xi - x;  if (ddx < 0) ddx = -ddx;
                        int ddy = yi - gy; if (ddy < 0) ddy = -ddy;
                        // displacement <= R only: outliers handled ONLY by list
                        if (ddx <= R && ddy <= R) {
                            int lx = xi - x0;
                            int ly = yi - ty0;
                            if (lx >= 0 && lx < TX && ly >= 0 && ly < TY) {
                                int t = ly * TX + lx;
                                int c = e * 4 + k;
                                tl[c] = t;
                                dp[c] = ds[k];
                                a0[c] = s0v[k]; a1[c] = s1v[k]; a2[c] = s2v[k];
                                atomicMin(&s_dmin[t], __float_as_int(ds[k]));
                            }
                        }
                    }
                }
            }
        }
        // Outlier min fold-in for this step's target rows.
        for (int j = tid; j < noutl; j += NT) {
            const float* e = list + (size_t)j * 8;
            int idx = __float_as_int(e[0]);
            if ((idx >> 19) == b) {
                int remt = idx & (HW - 1);
                int lx = (remt & (WW - 1)) - x0;
                int ly = (remt >> 10) - ty0;
                if (lx >= 0 && lx < TX && ly >= 0 && ly < TY)
                    atomicMin(&s_dmin[ly * TX + lx], __float_as_int(e[1]));
            }
        }
        __syncthreads();

        // Phase C: keep-test + accumulate (all operands in registers).
        #pragma unroll
        for (int c = 0; c < 8; ++c) {
            if (tl[c] >= 0) {
                float thresh = __int_as_float(s_dmin[tl[c]]) + SAME_RANGE;
                if (dp[c] <= thresh) {
                    atomicAdd(&s_s0[tl[c]], a0[c]);
                    atomicAdd(&s_s1[tl[c]], a1[c]);
                    atomicAdd(&s_s2[tl[c]], a2[c]);
                    atomicAdd(&s_cnt[tl[c]], 1.0f);
                }
            }
        }
        for (int j = tid; j < noutl; j += NT) {
            const float* e = list + (size_t)j * 8;
            int idx = __float_as_int(e[0]);
            if ((idx >> 19) == b) {
                int remt = idx & (HW - 1);
                int lx = (remt & (WW - 1)) - x0;
                int ly = (remt >> 10) - ty0;
                if (lx >= 0 && lx < TX && ly >= 0 && ly < TY) {
                    int t = ly * TX + lx;
                    float thresh = __int_as_float(s_dmin[t]) + SAME_RANGE;
                    if (e[1] <= thresh) {
                        atomicAdd(&s_s0[t], e[2]);
                        atomicAdd(&s_s1[t], e[3]);
                        atomicAdd(&s_s2[t], e[4]);
                        atomicAdd(&s_cnt[t], 1.0f);
                    }
                }
            }
        }
        __syncthreads();

        // Phase E: divide + float4 store + reset own slots (t<256 only; each
        // thread touches only its own 4 slots -> no store/reset hazard).
        if (tid < 256) {
            int lbase = tid * 4;
            int ly  = lbase >> 7;         // /TX (TX==128)
            int lx0 = lbase & (TX - 1);
            size_t orem = (size_t)(ty0 + ly) * WW + x0 + lx0;
            float4 r0, r1, r2;
            float* p0 = &r0.x; float* p1 = &r1.x; float* p2 = &r2.x;
            #pragma unroll
            for (int k = 0; k < 4; ++k) {
                int i = lbase + k;
                float c = s_cnt[i];
                if (c > 0.0f) {
                    p0[k] = s_s0[i] / c;
                    p1[k] = s_s1[i] / c;
                    p2[k] = s_s2[i] / c;
                } else {
                    p0[k] = 0.0f; p1[k] = 0.0f; p2[k] = 0.0f;
                }
                s_dmin[i] = D_SENT;
                s_s0[i] = 0.0f; s_s1[i] = 0.0f; s_s2[i] = 0.0f; s_cnt[i] = 0.0f;
            }
            *(float4*)(out + ((size_t)b * CC + 0) * HW + orem) = r0;
            *(float4*)(out + ((size_t)b * CC + 1) * HW + orem) = r1;
            *(float4*)(out + ((size_t)b * CC + 2) * HW + orem) = r2;
        }
        __syncthreads();   // resets visible before next step's atomicMin
    }
}

extern "C" void kernel_launch(void* const* d_in, const int* in_sizes, int n_in,
                              void* d_out, int out_size, void* d_ws, size_t ws_size,
                              hipStream_t stream) {
    const float* obj   = (const float*)d_in[0];
    const float* flow  = (const float*)d_in[1];
    const float* depth = (const float*)d_in[2];
    float* out = (float*)d_out;

    int*   counter = (int*)d_ws;
    float* list    = (float*)((char*)d_ws + 256);

    hipMemsetAsync(counter, 0, sizeof(int), stream);

    prep_kernel<<<dim3(NTOT / 4 / 256), dim3(256), 0, stream>>>(
        flow, depth, obj, counter, list);

    gather_kernel<<<dim3(WW / TX, HH / SEGY, BB), dim3(NT), 0, stream>>>(
        obj, flow, depth, counter, list, out);
}

// Round 8
// 164.722 us; speedup vs baseline: 1.3276x; 1.3276x over previous
//
#include <hip/hip_runtime.h>

// Problem constants (from reference setup_inputs)
#define BB 8
#define CC 3
#define HH 512
#define WW 1024
#define HW (HH * WW)            // 524288 = 2^19
#define NTOT (BB * HW)          // 4194304
#define SAME_RANGE 0.2f

// Partition of (source -> target) pairs:
//   displacement <= R in both coords  -> tile owning the TARGET via 40x40 halo
//   displacement  > R in either coord -> exact outlier list (~57 of 4.2M)
#define R 4
#define TX 32
#define TY 32
#define TT (TX * TY)            // 1024 targets per block
#define RX (TX + 2 * R)         // 40
#define RY (TY + 2 * R)         // 40
#define REG (RX * RY)           // 1600 halo sources per block
#define E_PER 7                 // ceil(1600 / 256)
#define CAP 16384               // outlier list capacity (~57 used)
#define D_SENTINEL 0x7F7F7F7F   // > any depth bit pattern (depth in [0,1))

// Fixed-point packing: field = (v + BIAS) * SCALE as u32; two fields per u64.
// Max per contribution: (16+6)*2^19 ~ 1.15e7; ~90 contributions ~ 1.0e9 < 2^32
// so fields never carry into each other. Decode: v*cnt = lo/SCALE - BIAS*cnt.
#define FP_BIAS  16.0f
#define FP_SCALE 524288.0f      // 2^19; quantization ~2e-6 << 0.108 threshold

__device__ __forceinline__ unsigned int fp_enc(float v) {
    return (unsigned int)__float2uint_rn((v + FP_BIAS) * FP_SCALE);
}

// Pass 1: outlier sources appended to global list (identical to round 4).
__global__ void prep_kernel(const float* __restrict__ flow,
                            const float* __restrict__ depth,
                            const float* __restrict__ obj,
                            int* __restrict__ counter,
                            float* __restrict__ list) {
    int tid = blockIdx.x * blockDim.x + threadIdx.x;
    int b = tid >> 19;
    int rem = tid & (HW - 1);
    int y = rem >> 10;
    int x = rem & (WW - 1);
    float fx = flow[(b * 2 + 0) * HW + rem] + (float)x;
    float fy = flow[(b * 2 + 1) * HW + rem] + (float)y;
    fx = fminf(fmaxf(fx, 0.0f), (float)(WW - 1));
    fy = fminf(fmaxf(fy, 0.0f), (float)(HH - 1));
    int xi = (int)rintf(fx);    // round-half-to-even == jnp.round
    int yi = (int)rintf(fy);
    int dx = xi - x; if (dx < 0) dx = -dx;
    int dy = yi - y; if (dy < 0) dy = -dy;
    if (dx > R || dy > R) {
        int idx = b * HW + yi * WW + xi;
        float d = depth[tid];
        int pos = atomicAdd(counter, 1);
        if (pos < CAP) {
            float* e = list + (size_t)pos * 8;
            e[0] = __int_as_float(idx);
            e[1] = d;
            e[2] = obj[(b * CC + 0) * HW + rem];
            e[3] = obj[(b * CC + 1) * HW + rem];
            e[4] = obj[(b * CC + 2) * HW + rem];
        }
    }
}

// Pass 2: round-4 LDS-scatter gather with u64 fixed-point packed accumulators:
// (o0,o1) and (o2,cnt) -> 2 x ds_add_u64 + 1 atomicMin per source (was 5
// atomics). Tests the LDS-atomic-throughput-wall theory.
__global__ __launch_bounds__(256) void gather_kernel(
        const float* __restrict__ obj,
        const float* __restrict__ flow,
        const float* __restrict__ depth,
        const int* __restrict__ counter,
        const float* __restrict__ list,
        float* __restrict__ out) {
    __shared__ int s_dmin[TT];
    __shared__ unsigned long long s_p01[TT];  // lo=enc(sum o0), hi=enc(sum o1)
    __shared__ unsigned long long s_p2c[TT];  // lo=enc(sum o2), hi=count

    int b = blockIdx.z;
    int tx0 = blockIdx.x * TX;
    int ty0 = blockIdx.y * TY;
    int tid = threadIdx.x;

    for (int i = tid; i < TT; i += 256) {
        s_dmin[i] = D_SENTINEL;
        s_p01[i] = 0ull;
        s_p2c[i] = 0ull;
    }
    __syncthreads();

    // Phase 1: halo sources -> LDS z-buffer min. Cache (tloc, d, rem) in regs.
    int   e_tloc[E_PER];
    float e_d[E_PER];
    int   e_rem[E_PER];
    #pragma unroll
    for (int e = 0; e < E_PER; ++e) {
        int i = tid + e * 256;
        int tloc = -1; float dv = 0.0f; int remv = 0;
        if (i < REG) {
            int sy = i / RX;
            int sx = i - sy * RX;
            int gy = ty0 - R + sy;
            int gx = tx0 - R + sx;
            if (gx >= 0 && gx < WW && gy >= 0 && gy < HH) {
                int rem = gy * WW + gx;
                float fx = flow[(b * 2 + 0) * HW + rem] + (float)gx;
                float fy = flow[(b * 2 + 1) * HW + rem] + (float)gy;
                fx = fminf(fmaxf(fx, 0.0f), (float)(WW - 1));
                fy = fminf(fmaxf(fy, 0.0f), (float)(HH - 1));
                int xi = (int)rintf(fx);
                int yi = (int)rintf(fy);
                int ddx = xi - gx; if (ddx < 0) ddx = -ddx;
                int ddy = yi - gy; if (ddy < 0) ddy = -ddy;
                // displacement <= R only: outliers handled EXCLUSIVELY by list
                if (ddx <= R && ddy <= R) {
                    int lx = xi - tx0;
                    int ly = yi - ty0;
                    if (lx >= 0 && lx < TX && ly >= 0 && ly < TY) {
                        tloc = ly * TX + lx;
                        dv = depth[b * HW + rem];
                        remv = rem;
                        atomicMin(&s_dmin[tloc], __float_as_int(dv));
                    }
                }
            }
        }
        e_tloc[e] = tloc; e_d[e] = dv; e_rem[e] = remv;
    }

    // Outlier phase 1: fold list depths into the LDS z-buffer.
    int noutl = *counter;
    if (noutl > CAP) noutl = CAP;
    for (int j = tid; j < noutl; j += 256) {
        const float* e = list + (size_t)j * 8;
        int idx = __float_as_int(e[0]);
        if ((idx >> 19) == b) {
            int remt = idx & (HW - 1);
            int lx = (remt & (WW - 1)) - tx0;
            int ly = (remt >> 10) - ty0;
            if (lx >= 0 && lx < TX && ly >= 0 && ly < TY)
                atomicMin(&s_dmin[ly * TX + lx], __float_as_int(e[1]));
        }
    }
    __syncthreads();

    // Phase 2: keep-test + packed accumulate (obj loaded lazily, keep-only).
    #pragma unroll
    for (int e = 0; e < E_PER; ++e) {
        int tloc = e_tloc[e];
        if (tloc >= 0) {
            float thresh = __int_as_float(s_dmin[tloc]) + SAME_RANGE;
            if (e_d[e] <= thresh) {
                int rem = e_rem[e];
                float o0 = obj[(b * CC + 0) * HW + rem];
                float o1 = obj[(b * CC + 1) * HW + rem];
                float o2 = obj[(b * CC + 2) * HW + rem];
                unsigned long long p01 =
                    (unsigned long long)fp_enc(o0) |
                    ((unsigned long long)fp_enc(o1) << 32);
                unsigned long long p2c =
                    (unsigned long long)fp_enc(o2) | (1ull << 32);
                atomicAdd(&s_p01[tloc], p01);
                atomicAdd(&s_p2c[tloc], p2c);
            }
        }
    }
    // Outlier phase 2.
    for (int j = tid; j < noutl; j += 256) {
        const float* e = list + (size_t)j * 8;
        int idx = __float_as_int(e[0]);
        if ((idx >> 19) == b) {
            int remt = idx & (HW - 1);
            int lx = (remt & (WW - 1)) - tx0;
            int ly = (remt >> 10) - ty0;
            if (lx >= 0 && lx < TX && ly >= 0 && ly < TY) {
                int t = ly * TX + lx;
                float thresh = __int_as_float(s_dmin[t]) + SAME_RANGE;
                if (e[1] <= thresh) {
                    unsigned long long p01 =
                        (unsigned long long)fp_enc(e[2]) |
                        ((unsigned long long)fp_enc(e[3]) << 32);
                    unsigned long long p2c =
                        (unsigned long long)fp_enc(e[4]) | (1ull << 32);
                    atomicAdd(&s_p01[t], p01);
                    atomicAdd(&s_p2c[t], p2c);
                }
            }
        }
    }
    __syncthreads();

    // Phase 3: decode + divide + coalesced store.
    // v_avg = field/(SCALE*cnt) - BIAS  (double decode: ~1e-7 error)
    for (int i = tid; i < TT; i += 256) {
        int lx = i & (TX - 1);
        int ly = i >> 5;            // TX == 32
        int orem = (ty0 + ly) * WW + (tx0 + lx);
        unsigned long long p01 = s_p01[i];
        unsigned long long p2c = s_p2c[i];
        unsigned int cnt = (unsigned int)(p2c >> 32);
        float r0 = 0.0f, r1 = 0.0f, r2 = 0.0f;
        if (cnt > 0) {
            double inv = 1.0 / ((double)FP_SCALE * (double)cnt);
            r0 = (float)((double)(unsigned int)(p01 & 0xffffffffu) * inv - (double)FP_BIAS);
            r1 = (float)((double)(unsigned int)(p01 >> 32)         * inv - (double)FP_BIAS);
            r2 = (float)((double)(unsigned int)(p2c & 0xffffffffu) * inv - (double)FP_BIAS);
        }
        out[(b * CC + 0) * HW + orem] = r0;
        out[(b * CC + 1) * HW + orem] = r1;
        out[(b * CC + 2) * HW + orem] = r2;
    }
}

extern "C" void kernel_launch(void* const* d_in, const int* in_sizes, int n_in,
                              void* d_out, int out_size, void* d_ws, size_t ws_size,
                              hipStream_t stream) {
    const float* obj   = (const float*)d_in[0];
    const float* flow  = (const float*)d_in[1];
    const float* depth = (const float*)d_in[2];
    float* out = (float*)d_out;

    int*   counter = (int*)d_ws;
    float* list    = (float*)((char*)d_ws + 256);

    hipMemsetAsync(counter, 0, sizeof(int), stream);

    prep_kernel<<<dim3(NTOT / 256), dim3(256), 0, stream>>>(
        flow, depth, obj, counter, list);

    gather_kernel<<<dim3(WW / TX, HH / TY, BB), dim3(256), 0, stream>>>(
        obj, flow, depth, counter, list, out);
}